// Round 5
// baseline (554.324 us; speedup 1.0000x reference)
//
#include <hip/hip_runtime.h>

#define TOK   65536      // B*N tokens
#define DIMS  256        // D
#define NCODE 2048       // K codebook
#define LOSSOFF 16777216
#define IDXOFF  16777217

typedef _Float16 f16x8 __attribute__((ext_vector_type(8)));
typedef _Float16 f16x4 __attribute__((ext_vector_type(4)));
typedef float    f32x4 __attribute__((ext_vector_type(4)));

__device__ __forceinline__ void ld16(void* lds, const void* g) {
  __builtin_amdgcn_global_load_lds(
      (const __attribute__((address_space(1))) unsigned int*)g,
      (__attribute__((address_space(3))) unsigned int*)lds, 16, 0, 0);
}
__device__ __forceinline__ unsigned long long umin64(unsigned long long a,
                                                     unsigned long long b) {
  return a < b ? a : b;
}

// ---------- K0a: transpose embed [D][K] -> embedT [K][D] fp32 + fp16 hi/lo planes
__global__ void k_prep(const float* __restrict__ embed, float* __restrict__ embedT,
                       _Float16* __restrict__ eTh, _Float16* __restrict__ eTl) {
  __shared__ float t[32][33];
  int tx = threadIdx.x & 31, ty = threadIdx.x >> 5;
  int k0 = blockIdx.x * 32, d0 = blockIdx.y * 32;
#pragma unroll
  for (int i = 0; i < 4; ++i) {
    int d = ty + i * 8;
    t[tx][d] = embed[(size_t)(d0 + d) * NCODE + k0 + tx];
  }
  __syncthreads();
#pragma unroll
  for (int i = 0; i < 4; ++i) {
    int kl = ty + i * 8;
    float v = t[kl][tx];
    size_t o = (size_t)(k0 + kl) * DIMS + d0 + tx;
    embedT[o] = v;
    _Float16 h = (_Float16)v;
    eTh[o] = h;
    eTl[o] = (_Float16)(v - (float)h);
  }
}

// ---------- K0b: e2[k] = sum_d embed[d][k]^2 (fp64 accumulate, deterministic)
__global__ void k_e2(const float* __restrict__ embed, float* __restrict__ e2) {
  int k = blockIdx.x * 256 + threadIdx.x;
  double a = 0.0;
  for (int d = 0; d < DIMS; ++d) {
    float v = embed[(size_t)d * NCODE + k];
    a += (double)v * (double)v;
  }
  e2[k] = (float)a;
}

// ---------- K0c: split x -> fp16 hi/lo planes; also init argmin cells + loss
__global__ void k_xsplit(const float* __restrict__ x, _Float16* __restrict__ xh,
                         _Float16* __restrict__ xl,
                         unsigned long long* __restrict__ part,
                         float* __restrict__ out) {
  int gid = blockIdx.x * 256 + threadIdx.x;
  if (gid < TOK) part[gid] = ~0ull;
  if (gid == 0) out[LOSSOFF] = 0.0f;
  size_t base = (size_t)gid;
#pragma unroll
  for (int i = 0; i < 8; ++i) {
    size_t o = (base + (size_t)i * 524288) * 4;
    f32x4 v = *(const f32x4*)&x[o];
    f16x4 h, l;
#pragma unroll
    for (int e = 0; e < 4; ++e) {
      h[e] = (_Float16)v[e];
      l[e] = (_Float16)(v[e] - (float)h[e]);
    }
    *(f16x4*)&xh[o] = h;
    *(f16x4*)&xl[o] = l;
  }
}

// ---------- K1: score GEMM — tri-buffered, counted-vmcnt phased schedule ----------
// Tile 256M x 128N, BK=32, 8 waves (4M x 2N), per-wave 64x64.
// LDS 144 KiB: 3 slots x (Ah+Al 32KB + Bh+Bl 16KB). Prefetch depth 2:
// stage(c+2) issued during chunk c; one s_waitcnt vmcnt(6) per chunk (never 0
// until the tail). Slot (c+2)%3 == (c-1)%3, whose reads completed a barrier ago.
#define MM(ah_, al_, bh_, bl_, a_) do { \
  a_ = __builtin_amdgcn_mfma_f32_16x16x32_f16(ah_, bh_, a_, 0, 0, 0); \
  a_ = __builtin_amdgcn_mfma_f32_16x16x32_f16(ah_, bl_, a_, 0, 0, 0); \
  a_ = __builtin_amdgcn_mfma_f32_16x16x32_f16(al_, bh_, a_, 0, 0, 0); } while (0)

#define SBAR_PRE do { __builtin_amdgcn_sched_barrier(0); __builtin_amdgcn_s_barrier(); \
  asm volatile("s_waitcnt lgkmcnt(0)" ::: "memory"); __builtin_amdgcn_sched_barrier(0); \
  __builtin_amdgcn_s_setprio(1); } while (0)

#define SBAR_POST do { __builtin_amdgcn_s_setprio(0); __builtin_amdgcn_sched_barrier(0); \
  __builtin_amdgcn_s_barrier(); } while (0)

__global__ __launch_bounds__(512, 1) void k_score(
    const _Float16* __restrict__ xh, const _Float16* __restrict__ xl,
    const _Float16* __restrict__ eTh, const _Float16* __restrict__ eTl,
    const float* __restrict__ e2, unsigned long long* __restrict__ part) {
  __shared__ __attribute__((aligned(16))) _Float16 Ah[3][256 * 32];
  __shared__ __attribute__((aligned(16))) _Float16 Al[3][256 * 32];
  __shared__ __attribute__((aligned(16))) _Float16 Bh[3][128 * 32];
  __shared__ __attribute__((aligned(16))) _Float16 Bl[3][128 * 32];

  int tid = threadIdx.x, lane = tid & 63, wid = tid >> 6;
  int wm = wid >> 1, wn = wid & 1;
  int bid = blockIdx.x;
  int wg = (bid & 7) * 512 + (bid >> 3);   // XCD-bijective (4096 = 8*512)
  int mblk = wg >> 4, nblk = wg & 15;
  int t0 = mblk * 256, c0 = nblk * 128;
  int col = lane & 15, kg = lane >> 4;

  f32x4 acc[4][4] = {};

  // LDS swizzle: physical granule p = logical g ^ ((row>>1)&3); linear LDS dest,
  // inverse-permuted GLOBAL source, same XOR on the read side (rule #21).
  auto stageA = [&](int ck, int slot) {
    int kb = ck * 32;
#pragma unroll
    for (int q = 0; q < 2; ++q) {
      int i = q * 512 + wid * 64 + lane;
      int row = i >> 2;
      int g = (i & 3) ^ ((row >> 1) & 3);
      size_t src = (size_t)(t0 + row) * DIMS + kb + g * 8;
      ld16(&Ah[slot][(q * 512 + wid * 64) * 8], &xh[src]);
      ld16(&Al[slot][(q * 512 + wid * 64) * 8], &xl[src]);
    }
  };
  auto stageB = [&](int ck, int slot) {
    int kb = ck * 32;
    int i = wid * 64 + lane;
    int row = i >> 2;
    int g = (i & 3) ^ ((row >> 1) & 3);
    size_t src = (size_t)(c0 + row) * DIMS + kb + g * 8;
    ld16(&Bh[slot][(wid * 64) * 8], &eTh[src]);
    ld16(&Bl[slot][(wid * 64) * 8], &eTl[src]);
  };
  auto rdA = [&](int slot, int mf, f16x8& h, f16x8& l) {
    int row = wm * 64 + mf * 16 + col;
    int off = row * 32 + (kg ^ ((row >> 1) & 3)) * 8;
    h = *(const f16x8*)&Ah[slot][off];
    l = *(const f16x8*)&Al[slot][off];
  };
  auto rdB = [&](int slot, int nf, f16x8& h, f16x8& l) {
    int row = wn * 64 + nf * 16 + col;
    int off = row * 32 + (kg ^ ((row >> 1) & 3)) * 8;
    h = *(const f16x8*)&Bh[slot][off];
    l = *(const f16x8*)&Bl[slot][off];
  };

  // prologue: two chunks staged; drain only the oldest (stage 0)
  stageA(0, 0); stageB(0, 0);
  stageA(1, 1); stageB(1, 1);
  asm volatile("s_waitcnt vmcnt(6)" ::: "memory");
  __builtin_amdgcn_sched_barrier(0);
  __builtin_amdgcn_s_barrier();

#pragma unroll
  for (int c = 0; c < 8; ++c) {
    int slot = c % 3;
    f16x8 a0h, a0l, a1h, a1l, a2h, a2l, a3h, a3l;
    f16x8 b0h, b0l, b1h, b1l, b2h, b2l, b3h, b3l;
    // P1: quadrant (m0-1, n0-1)
    if (c < 6) stageA(c + 2, (c + 2) % 3);
    rdA(slot, 0, a0h, a0l); rdA(slot, 1, a1h, a1l);
    rdB(slot, 0, b0h, b0l); rdB(slot, 1, b1h, b1l);
    SBAR_PRE;
    MM(a0h, a0l, b0h, b0l, acc[0][0]); MM(a0h, a0l, b1h, b1l, acc[0][1]);
    MM(a1h, a1l, b0h, b0l, acc[1][0]); MM(a1h, a1l, b1h, b1l, acc[1][1]);
    SBAR_POST;
    // P2: quadrant (m0-1, n2-3)
    if (c < 6) stageB(c + 2, (c + 2) % 3);
    rdB(slot, 2, b2h, b2l); rdB(slot, 3, b3h, b3l);
    SBAR_PRE;
    MM(a0h, a0l, b2h, b2l, acc[0][2]); MM(a0h, a0l, b3h, b3l, acc[0][3]);
    MM(a1h, a1l, b2h, b2l, acc[1][2]); MM(a1h, a1l, b3h, b3l, acc[1][3]);
    SBAR_POST;
    // P3: quadrant (m2-3, n0-1)
    rdA(slot, 2, a2h, a2l); rdA(slot, 3, a3h, a3l);
    SBAR_PRE;
    MM(a2h, a2l, b0h, b0l, acc[2][0]); MM(a2h, a2l, b1h, b1l, acc[2][1]);
    MM(a3h, a3l, b0h, b0l, acc[3][0]); MM(a3h, a3l, b1h, b1l, acc[3][1]);
    SBAR_POST;
    // P4: quadrant (m2-3, n2-3) + counted chunk-boundary wait
    SBAR_PRE;
    MM(a2h, a2l, b2h, b2l, acc[2][2]); MM(a2h, a2l, b3h, b3l, acc[2][3]);
    MM(a3h, a3l, b2h, b2l, acc[3][2]); MM(a3h, a3l, b3h, b3l, acc[3][3]);
    __builtin_amdgcn_s_setprio(0);
    __builtin_amdgcn_sched_barrier(0);
    if (c < 6) {
      asm volatile("s_waitcnt vmcnt(6)" ::: "memory");   // stage(c+1) done
    } else if (c == 6) {
      asm volatile("s_waitcnt vmcnt(0)" ::: "memory");   // stage(7) done (tail)
    }
    __builtin_amdgcn_sched_barrier(0);
    if (c < 7) __builtin_amdgcn_s_barrier();
  }

  // epilogue: s = e2 - 2*dot; sortable u64 key (low 32 = code -> lowest index wins)
  float e2n[4];
#pragma unroll
  for (int n = 0; n < 4; ++n) e2n[n] = e2[c0 + wn * 64 + n * 16 + col];
#pragma unroll
  for (int m = 0; m < 4; ++m)
#pragma unroll
    for (int r = 0; r < 4; ++r) {
      unsigned long long best = ~0ull;
#pragma unroll
      for (int n = 0; n < 4; ++n) {
        float s = e2n[n] - 2.0f * acc[m][n][r];
        unsigned u = __float_as_uint(s);
        u ^= (u & 0x80000000u) ? 0xFFFFFFFFu : 0x80000000u;
        best = umin64(best, ((unsigned long long)u << 32) |
                            (unsigned)(c0 + wn * 64 + n * 16 + col));
      }
#pragma unroll
      for (int off = 1; off < 16; off <<= 1)
        best = umin64(best, __shfl_xor(best, off, 64));
      if (col == 0)
        atomicMin(&part[t0 + wm * 64 + m * 16 + kg * 4 + r], best);
    }
}

// ---------- K3: gather codes, STE output, indices, commitment loss ----------
__global__ void k_gather(const float* __restrict__ x, const float* __restrict__ embedT,
                         const unsigned long long* __restrict__ part,
                         float* __restrict__ out) {
  int wid = threadIdx.x >> 6, lane = threadIdx.x & 63;
  int gw = blockIdx.x * 4 + wid;          // 8192 waves, 8 tokens each
  float s = 0.0f;
#pragma unroll
  for (int t = 0; t < 8; ++t) {
    int token = gw * 8 + t;
    int code = (int)(part[token] & 0xFFFFFFFFull);   // broadcast load
    if (lane == 0) out[IDXOFF + token] = (float)code;
    f32x4 q  = *(const f32x4*)&embedT[(size_t)code * DIMS + lane * 4];
    f32x4 xv = *(const f32x4*)&x[(size_t)token * DIMS + lane * 4];
    f32x4 d = q - xv;
    *(f32x4*)&out[(size_t)token * DIMS + lane * 4] = xv + d;  // STE: x + (q - x)
    s += d[0] * d[0] + d[1] * d[1] + d[2] * d[2] + d[3] * d[3];
  }
  for (int off = 32; off; off >>= 1) s += __shfl_xor(s, off, 64);
  __shared__ float red[4];
  if (lane == 0) red[wid] = s;
  __syncthreads();
  if (threadIdx.x == 0) {
    float tsum = (red[0] + red[1] + red[2] + red[3]) * (0.25f / 16777216.0f);
    atomicAdd(&out[LOSSOFF], tsum);
  }
}

extern "C" void kernel_launch(void* const* d_in, const int* in_sizes, int n_in,
                              void* d_out, int out_size, void* d_ws, size_t ws_size,
                              hipStream_t stream) {
  const float* x     = (const float*)d_in[0];
  const float* embed = (const float*)d_in[1];
  float* out = (float*)d_out;
  // x hi/lo fp16 planes live in the quantize region of d_out (exactly 64 MB),
  // consumed by k_score then overwritten by k_gather.
  _Float16* xh = (_Float16*)d_out;
  _Float16* xl = (_Float16*)((char*)d_out + (32u << 20));
  char* w = (char*)d_ws;
  _Float16* eTh    = (_Float16*)w;                               // 1 MB
  _Float16* eTl    = (_Float16*)(w + (1u << 20));                // 1 MB
  float*    embedT = (float*)(w + (2u << 20));                   // 2 MB
  float*    e2     = (float*)(w + (4u << 20));                   // 8 KB
  unsigned long long* part = (unsigned long long*)(w + (4u << 20) + (1u << 15)); // 512 KB

  hipLaunchKernelGGL(k_prep,   dim3(NCODE / 32, DIMS / 32), dim3(256), 0, stream, embed, embedT, eTh, eTl);
  hipLaunchKernelGGL(k_e2,     dim3(NCODE / 256),           dim3(256), 0, stream, embed, e2);
  hipLaunchKernelGGL(k_xsplit, dim3(2048),                  dim3(256), 0, stream, x, xh, xl, part, out);
  hipLaunchKernelGGL(k_score,  dim3(4096),                  dim3(512), 0, stream, xh, xl, eTh, eTl, e2, part);
  hipLaunchKernelGGL(k_gather, dim3(2048),                  dim3(256), 0, stream, x, embedT, part, out);
}

// Round 7
// 508.472 us; speedup vs baseline: 1.0902x; 1.0902x over previous
//
#include <hip/hip_runtime.h>

#define TOK   65536      // B*N tokens
#define DIMS  256        // D
#define NCODE 2048       // K codebook
#define LOSSOFF 16777216
#define IDXOFF  16777217

typedef _Float16 f16x8 __attribute__((ext_vector_type(8)));
typedef _Float16 f16x4 __attribute__((ext_vector_type(4)));
typedef float    f32x4 __attribute__((ext_vector_type(4)));

__device__ __forceinline__ void ld16(void* lds, const void* g) {
  __builtin_amdgcn_global_load_lds(
      (const __attribute__((address_space(1))) unsigned int*)g,
      (__attribute__((address_space(3))) unsigned int*)lds, 16, 0, 0);
}
__device__ __forceinline__ unsigned long long umin64(unsigned long long a,
                                                     unsigned long long b) {
  return a < b ? a : b;
}

// ---------- K0a: transpose embed [D][K] -> embedT [K][D] fp32 + fp16 hi/lo planes
__global__ void k_prep(const float* __restrict__ embed, float* __restrict__ embedT,
                       _Float16* __restrict__ eTh, _Float16* __restrict__ eTl) {
  __shared__ float t[32][33];
  int tx = threadIdx.x & 31, ty = threadIdx.x >> 5;
  int k0 = blockIdx.x * 32, d0 = blockIdx.y * 32;
#pragma unroll
  for (int i = 0; i < 4; ++i) {
    int d = ty + i * 8;
    t[tx][d] = embed[(size_t)(d0 + d) * NCODE + k0 + tx];
  }
  __syncthreads();
#pragma unroll
  for (int i = 0; i < 4; ++i) {
    int kl = ty + i * 8;
    float v = t[kl][tx];
    size_t o = (size_t)(k0 + kl) * DIMS + d0 + tx;
    embedT[o] = v;
    _Float16 h = (_Float16)v;
    eTh[o] = h;
    eTl[o] = (_Float16)(v - (float)h);
  }
}

// ---------- K0b: e2[k] = sum_d embed[d][k]^2 (fp64 accumulate, deterministic)
__global__ void k_e2(const float* __restrict__ embed, float* __restrict__ e2) {
  int k = blockIdx.x * 256 + threadIdx.x;
  double a = 0.0;
  for (int d = 0; d < DIMS; ++d) {
    float v = embed[(size_t)d * NCODE + k];
    a += (double)v * (double)v;
  }
  e2[k] = (float)a;
}

// ---------- K0c: split x -> fp16 hi/lo planes; also init argmin cells + loss
__global__ void k_xsplit(const float* __restrict__ x, _Float16* __restrict__ xh,
                         _Float16* __restrict__ xl,
                         unsigned long long* __restrict__ part,
                         float* __restrict__ out) {
  int gid = blockIdx.x * 256 + threadIdx.x;
  if (gid < TOK) part[gid] = ~0ull;
  if (gid == 0) out[LOSSOFF] = 0.0f;
  size_t base = (size_t)gid;
#pragma unroll
  for (int i = 0; i < 8; ++i) {
    size_t o = (base + (size_t)i * 524288) * 4;
    f32x4 v = *(const f32x4*)&x[o];
    f16x4 h, l;
#pragma unroll
    for (int e = 0; e < 4; ++e) {
      h[e] = (_Float16)v[e];
      l[e] = (_Float16)(v[e] - (float)h[e]);
    }
    *(f16x4*)&xh[o] = h;
    *(f16x4*)&xl[o] = l;
  }
}

// ---------- K1: score GEMM — tri-buffered, ONE barrier + ONE counted vmcnt per chunk
// Tile 256M x 128N, BK=32, 8 waves (4M x 2N), per-wave 64x64. LDS 144 KiB.
// Chunk c reads slot c%3 (written 2 chunks ago); stage(c+2) -> slot (c-1)%3,
// whose reads completed before the previous boundary barrier. No intra-chunk
// barriers needed; compiler auto-emits counted lgkmcnt for ds_read->MFMA deps.
#define MM(ah_, al_, bh_, bl_, a_) do { \
  a_ = __builtin_amdgcn_mfma_f32_16x16x32_f16(ah_, bh_, a_, 0, 0, 0); \
  a_ = __builtin_amdgcn_mfma_f32_16x16x32_f16(ah_, bl_, a_, 0, 0, 0); \
  a_ = __builtin_amdgcn_mfma_f32_16x16x32_f16(al_, bh_, a_, 0, 0, 0); } while (0)

__global__ __launch_bounds__(512, 1) void k_score(
    const _Float16* __restrict__ xh, const _Float16* __restrict__ xl,
    const _Float16* __restrict__ eTh, const _Float16* __restrict__ eTl,
    const float* __restrict__ e2, unsigned long long* __restrict__ part) {
  __shared__ __attribute__((aligned(16))) _Float16 Ah[3][256 * 32];
  __shared__ __attribute__((aligned(16))) _Float16 Al[3][256 * 32];
  __shared__ __attribute__((aligned(16))) _Float16 Bh[3][128 * 32];
  __shared__ __attribute__((aligned(16))) _Float16 Bl[3][128 * 32];

  int tid = threadIdx.x, lane = tid & 63, wid = tid >> 6;
  int wm = wid >> 1, wn = wid & 1;
  int bid = blockIdx.x;
  int wg = (bid & 7) * 512 + (bid >> 3);   // XCD-bijective (4096 = 8*512)
  int mblk = wg >> 4, nblk = wg & 15;
  int t0 = mblk * 256, c0 = nblk * 128;
  int col = lane & 15, kg = lane >> 4;

  f32x4 acc[4][4] = {};

  // LDS swizzle: physical granule p = logical g ^ ((row>>1)&3); linear LDS dest,
  // inverse-permuted GLOBAL source, same XOR on the read side (rule #21).
  auto stageA = [&](int ck, int slot) {
    int kb = ck * 32;
#pragma unroll
    for (int q = 0; q < 2; ++q) {
      int i = q * 512 + wid * 64 + lane;
      int row = i >> 2;
      int g = (i & 3) ^ ((row >> 1) & 3);
      size_t src = (size_t)(t0 + row) * DIMS + kb + g * 8;
      ld16(&Ah[slot][(q * 512 + wid * 64) * 8], &xh[src]);
      ld16(&Al[slot][(q * 512 + wid * 64) * 8], &xl[src]);
    }
  };
  auto stageB = [&](int ck, int slot) {
    int kb = ck * 32;
    int i = wid * 64 + lane;
    int row = i >> 2;
    int g = (i & 3) ^ ((row >> 1) & 3);
    size_t src = (size_t)(c0 + row) * DIMS + kb + g * 8;
    ld16(&Bh[slot][(wid * 64) * 8], &eTh[src]);
    ld16(&Bl[slot][(wid * 64) * 8], &eTl[src]);
  };
  auto rdA = [&](int slot, int mf, f16x8& h, f16x8& l) {
    int row = wm * 64 + mf * 16 + col;
    int off = row * 32 + (kg ^ ((row >> 1) & 3)) * 8;
    h = *(const f16x8*)&Ah[slot][off];
    l = *(const f16x8*)&Al[slot][off];
  };
  auto rdB = [&](int slot, int nf, f16x8& h, f16x8& l) {
    int row = wn * 64 + nf * 16 + col;
    int off = row * 32 + (kg ^ ((row >> 1) & 3)) * 8;
    h = *(const f16x8*)&Bh[slot][off];
    l = *(const f16x8*)&Bl[slot][off];
  };

  // prologue: two chunks staged; drain only the oldest (stage 0)
  stageA(0, 0); stageB(0, 0);
  stageA(1, 1); stageB(1, 1);
  asm volatile("s_waitcnt vmcnt(6)" ::: "memory");
  __builtin_amdgcn_sched_barrier(0);
  __builtin_amdgcn_s_barrier();
  __builtin_amdgcn_sched_barrier(0);

#pragma unroll
  for (int c = 0; c < 8; ++c) {
    int slot = c % 3;
    // 1) all 16 frag reads up front — latency starts ticking now
    f16x8 ah[4], al[4], bh[4], bl[4];
#pragma unroll
    for (int m = 0; m < 4; ++m) rdA(slot, m, ah[m], al[m]);
#pragma unroll
    for (int n = 0; n < 4; ++n) rdB(slot, n, bh[n], bl[n]);
    __builtin_amdgcn_sched_barrier(0);
    // 2) prefetch issues for chunk c+2 (slot (c-1)%3, reads long done)
    if (c < 6) { stageA(c + 2, (c + 2) % 3); stageB(c + 2, (c + 2) % 3); }
    __builtin_amdgcn_sched_barrier(0);
    // 3) 48 MFMA; compiler inserts counted lgkmcnt before first consumers
    __builtin_amdgcn_s_setprio(1);
#pragma unroll
    for (int m = 0; m < 4; ++m)
#pragma unroll
      for (int n = 0; n < 4; ++n)
        MM(ah[m], al[m], bh[n], bl[n], acc[m][n]);
    __builtin_amdgcn_s_setprio(0);
    __builtin_amdgcn_sched_barrier(0);
    // 4) chunk boundary: counted wait (never 0 until tail) + single barrier
    if (c < 6) {
      asm volatile("s_waitcnt vmcnt(6)" ::: "memory");   // stage(c+1) landed
    } else if (c == 6) {
      asm volatile("s_waitcnt vmcnt(0)" ::: "memory");   // stage(7) landed (tail)
    }
    __builtin_amdgcn_sched_barrier(0);
    if (c < 7) __builtin_amdgcn_s_barrier();
    __builtin_amdgcn_sched_barrier(0);
  }

  // epilogue: s = e2 - 2*dot; sortable u64 key (low 32 = code -> lowest index wins)
  float e2n[4];
#pragma unroll
  for (int n = 0; n < 4; ++n) e2n[n] = e2[c0 + wn * 64 + n * 16 + col];
#pragma unroll
  for (int m = 0; m < 4; ++m)
#pragma unroll
    for (int r = 0; r < 4; ++r) {
      unsigned long long best = ~0ull;
#pragma unroll
      for (int n = 0; n < 4; ++n) {
        float s = e2n[n] - 2.0f * acc[m][n][r];
        unsigned u = __float_as_uint(s);
        u ^= (u & 0x80000000u) ? 0xFFFFFFFFu : 0x80000000u;
        best = umin64(best, ((unsigned long long)u << 32) |
                            (unsigned)(c0 + wn * 64 + n * 16 + col));
      }
#pragma unroll
      for (int off = 1; off < 16; off <<= 1)
        best = umin64(best, __shfl_xor(best, off, 64));
      if (col == 0)
        atomicMin(&part[t0 + wm * 64 + m * 16 + kg * 4 + r], best);
    }
}

// ---------- K3: gather codes, STE output, indices, commitment loss ----------
__global__ void k_gather(const float* __restrict__ x, const float* __restrict__ embedT,
                         const unsigned long long* __restrict__ part,
                         float* __restrict__ out) {
  int wid = threadIdx.x >> 6, lane = threadIdx.x & 63;
  int gw = blockIdx.x * 4 + wid;          // 8192 waves, 8 tokens each
  float s = 0.0f;
#pragma unroll
  for (int t = 0; t < 8; ++t) {
    int token = gw * 8 + t;
    int code = (int)(part[token] & 0xFFFFFFFFull);   // broadcast load
    if (lane == 0) out[IDXOFF + token] = (float)code;
    f32x4 q  = *(const f32x4*)&embedT[(size_t)code * DIMS + lane * 4];
    f32x4 xv = *(const f32x4*)&x[(size_t)token * DIMS + lane * 4];
    f32x4 d = q - xv;
    *(f32x4*)&out[(size_t)token * DIMS + lane * 4] = xv + d;  // STE: x + (q - x)
    s += d[0] * d[0] + d[1] * d[1] + d[2] * d[2] + d[3] * d[3];
  }
  for (int off = 32; off; off >>= 1) s += __shfl_xor(s, off, 64);
  __shared__ float red[4];
  if (lane == 0) red[wid] = s;
  __syncthreads();
  if (threadIdx.x == 0) {
    float tsum = (red[0] + red[1] + red[2] + red[3]) * (0.25f / 16777216.0f);
    atomicAdd(&out[LOSSOFF], tsum);
  }
}

extern "C" void kernel_launch(void* const* d_in, const int* in_sizes, int n_in,
                              void* d_out, int out_size, void* d_ws, size_t ws_size,
                              hipStream_t stream) {
  const float* x     = (const float*)d_in[0];
  const float* embed = (const float*)d_in[1];
  float* out = (float*)d_out;
  // x hi/lo fp16 planes live in the quantize region of d_out (exactly 64 MB),
  // consumed by k_score then overwritten by k_gather.
  _Float16* xh = (_Float16*)d_out;
  _Float16* xl = (_Float16*)((char*)d_out + (32u << 20));
  char* w = (char*)d_ws;
  _Float16* eTh    = (_Float16*)w;                               // 1 MB
  _Float16* eTl    = (_Float16*)(w + (1u << 20));                // 1 MB
  float*    embedT = (float*)(w + (2u << 20));                   // 2 MB
  float*    e2     = (float*)(w + (4u << 20));                   // 8 KB
  unsigned long long* part = (unsigned long long*)(w + (4u << 20) + (1u << 15)); // 512 KB

  hipLaunchKernelGGL(k_prep,   dim3(NCODE / 32, DIMS / 32), dim3(256), 0, stream, embed, embedT, eTh, eTl);
  hipLaunchKernelGGL(k_e2,     dim3(NCODE / 256),           dim3(256), 0, stream, embed, e2);
  hipLaunchKernelGGL(k_xsplit, dim3(2048),                  dim3(256), 0, stream, x, xh, xl, part, out);
  hipLaunchKernelGGL(k_score,  dim3(4096),                  dim3(512), 0, stream, xh, xl, eTh, eTl, e2, part);
  hipLaunchKernelGGL(k_gather, dim3(2048),                  dim3(256), 0, stream, x, embedT, part, out);
}